// Round 6
// baseline (51.238 us; speedup 1.0000x reference)
//
#include <hip/hip_runtime.h>

namespace {

template<int CTRL, int RM>
__device__ __forceinline__ float dpp_mov0(float v) {
  return __int_as_float(__builtin_amdgcn_update_dpp(
      0, __float_as_int(v), CTRL, RM, 0xF, false));
}
template<int CTRL, int RM>
__device__ __forceinline__ float dpp_mov1(float v) {
  return __int_as_float(__builtin_amdgcn_update_dpp(
      0x3f800000, __float_as_int(v), CTRL, RM, 0xF, false));
}

__device__ __forceinline__ float rl(float v, int k) {
  return __int_as_float(__builtin_amdgcn_readlane(__float_as_int(v), k));
}

// lhs = I - h*A = diag(d_n) + h r_i r_k (k<i), h=dt/2, r_n=sqrt(2n+1),
// d_n=1+h(n+1). y = A_bar x via one joint 2-var linear-recurrence DPP scan
// (HW-verified rounds 1-5, absmax 2.4e-4). Coefs hoisted (data-independent).
struct Hoist {
  float cs0, cs1, cs2, cs3, cs4, cs5;
  float gs0, gs1, gs2, gs3, gs4, gs5;
  float r, inv_d, hr, alpha, k2;
};

__device__ __forceinline__ Hoist make_hoist(float dt, int n) {
  float h = 0.5f * dt, fn = (float)n;
  float r = sqrtf(2.f * fn + 1.f);
  float d = 1.f + h * (fn + 1.f);
  float inv_d = 1.f / d;
  float g = (1.f - h * fn) * inv_d;
  float c = g - 1.f;                  // = -h r^2 / d
  Hoist H;
  H.r = r; H.inv_d = inv_d; H.hr = h * r;
  H.alpha = 1.f + h * fn;
  H.k2 = r * (2.f - d) * inv_d;
#define COEF_STEP(IDX, CTRL, RM)                                        \
  H.cs##IDX = c; H.gs##IDX = g;                                         \
  { float cP = dpp_mov0<CTRL, RM>(c);                                   \
    float gP = dpp_mov1<CTRL, RM>(g);                                   \
    c = fmaf(g, cP, c); g = g * gP; }
  COEF_STEP(0, 0x111, 0xF)   // row_shr:1
  COEF_STEP(1, 0x112, 0xF)   // row_shr:2
  COEF_STEP(2, 0x114, 0xF)   // row_shr:4
  COEF_STEP(3, 0x118, 0xF)   // row_shr:8
  COEF_STEP(4, 0x142, 0xA)   // row_bcast15 -> rows 1,3
  COEF_STEP(5, 0x143, 0xC)   // row_bcast31 -> rows 2,3
#undef COEF_STEP
  return H;
}

__device__ __forceinline__ float abar_apply(float x, const Hoist& H) {
  float w1 = H.r * x, w2 = H.k2 * x;
#define APPLY_STEP(IDX, CTRL, RM)                                       \
  { float w1P = dpp_mov0<CTRL, RM>(w1);                                 \
    float w2P = dpp_mov0<CTRL, RM>(w2);                                 \
    w2 = fmaf(H.cs##IDX, w1P, fmaf(H.gs##IDX, w2P, w2));                \
    w1 += w1P; }
  APPLY_STEP(0, 0x111, 0xF)
  APPLY_STEP(1, 0x112, 0xF)
  APPLY_STEP(2, 0x114, 0xF)
  APPLY_STEP(3, 0x118, 0xF)
  APPLY_STEP(4, 0x142, 0xA)
  APPLY_STEP(5, 0x143, 0xC)
#undef APPLY_STEP
  float tp = dpp_mov0<0x138, 0xF>(w2);           // wave_shr:1 -> T_{i-1}
  return H.inv_d * fmaf(-H.hr, w1 + tp, H.alpha * x);
}

template<int CTRL, int RM>
__device__ __forceinline__ void linrec_step(float& G, float& W) {
  float Wo = dpp_mov0<CTRL, RM>(W);
  float Go = dpp_mov1<CTRL, RM>(G);
  W = fmaf(G, Wo, W);
  G *= Go;
}
__device__ __forceinline__ float lhs_solve(float z, const Hoist& H) {
  float G = H.gs0, W = H.r * z * H.inv_d;
  linrec_step<0x111, 0xF>(G, W);
  linrec_step<0x112, 0xF>(G, W);
  linrec_step<0x114, 0xF>(G, W);
  linrec_step<0x118, 0xF>(G, W);
  linrec_step<0x142, 0xA>(G, W);
  linrec_step<0x143, 0xC>(G, W);
  float sp = dpp_mov0<0x138, 0xF>(W);
  return (z - H.hr * sp) * H.inv_d;
}

__device__ __forceinline__ float softplus_dt(float ldt) {
  return log1pf(expf(ldt)) + 1e-6f;
}

// pc[k] = M[lane][k] from global (L2-hot) into registers. VMEM only.
__device__ __forceinline__ void load_row_g(const float* __restrict__ base,
                                           float (&pc)[64]) {
  const float4* p4 = (const float4*)base;
  #pragma unroll
  for (int q = 0; q < 16; ++q) {
    float4 f = p4[q];
    pc[4*q+0] = f.x; pc[4*q+1] = f.y; pc[4*q+2] = f.z; pc[4*q+3] = f.w;
  }
}

// res[lane] = sum_k pc[k]*u[k]; u distributed, broadcast via readlane.
__device__ __forceinline__ float qapply(const float (&pc)[64], float u) {
  float a0 = 0.f, a1 = 0.f, a2 = 0.f, a3 = 0.f;
  #pragma unroll
  for (int k = 0; k < 64; k += 4) {
    a0 = fmaf(pc[k + 0], rl(u, k + 0), a0);
    a1 = fmaf(pc[k + 1], rl(u, k + 1), a1);
    a2 = fmaf(pc[k + 2], rl(u, k + 2), a2);
    a3 = fmaf(pc[k + 3], rl(u, k + 3), a3);
  }
  return (a0 + a1) + (a2 + a3);
}

// streaming matvec from global row (one float4 live at a time)
__device__ __forceinline__ float grow_matvec(const float* __restrict__ M,
                                             float u, int lane) {
  float a0 = 0.f, a1 = 0.f, a2 = 0.f, a3 = 0.f;
  const float4* m4 = (const float4*)(M + lane * 64);
  #pragma unroll
  for (int q = 0; q < 16; ++q) {
    float4 f = m4[q];
    a0 = fmaf(f.x, rl(u, 4 * q + 0), a0);
    a1 = fmaf(f.y, rl(u, 4 * q + 1), a1);
    a2 = fmaf(f.z, rl(u, 4 * q + 2), a2);
    a3 = fmaf(f.w, rl(u, 4 * q + 3), a3);
  }
  return (a0 + a1) + (a2 + a3);
}

} // namespace

// Prep: block m chains e_m through 64 applies.
//   s=32: col m of A32 -> row-major A32c[n][k]
//   s=64: col m of A64 -> QROW[m][k] = Q-row m (coalesced)
__global__ __launch_bounds__(64) void hippo_pow(const float* __restrict__ ldt_p,
                                                float* __restrict__ A32c,
                                                float* __restrict__ QROW) {
  const int lane = threadIdx.x;
  const int m = blockIdx.x;
  const float dt = softplus_dt(ldt_p[0]);
  const Hoist H = make_hoist(dt, lane);
  float x = (lane == m) ? 1.f : 0.f;
  #pragma unroll 1
  for (int s = 0; s < 32; ++s) x = abar_apply(x, H);
  A32c[lane * 64 + m] = x;
  #pragma unroll 1
  for (int s = 0; s < 32; ++s) x = abar_apply(x, H);
  QROW[m * 64 + lane] = x;
}

// Phase 1: chains only. 3 waves, NO LDS, NO barrier. All stores coalesced.
//  w0: V[0..31]; w1: V[32..63] (A32 seed); w2: U chain (register matvecs).
__global__ __launch_bounds__(192) void hippo_chains(
    const float* __restrict__ B, const float* __restrict__ C,
    const float* __restrict__ ldt_p, const float* __restrict__ A32c,
    const float* __restrict__ QROW, float* __restrict__ Vg,
    float* __restrict__ Ug, int NI) {
  const int d = blockIdx.x;
  const int tau = threadIdx.x;
  const int lane = tau & 63;
  const int w = tau >> 6;
  const float dt = softplus_dt(ldt_p[0]);
  float* Vd = Vg + (size_t)d * 4096;   // [64][64]
  float* Ud = Ug + (size_t)d * 2048;   // [32][64]

  if (w == 0) {
    const Hoist H = make_hoist(dt, lane);
    float v = lhs_solve(dt * B[d * 64 + lane], H);
    #pragma unroll 1
    for (int j = 0; j < 32; ++j) {
      Vd[j * 64 + lane] = v;                    // coalesced
      if (j < 31) v = abar_apply(v, H);
    }
  } else if (w == 1) {
    const Hoist H = make_hoist(dt, lane);
    float bb = lhs_solve(dt * B[d * 64 + lane], H);
    float v = grow_matvec(A32c, bb, lane);      // V32 = A32 * B_bar
    #pragma unroll 1
    for (int j = 32; j < 64; ++j) {
      Vd[j * 64 + lane] = v;
      if (j < 63) v = abar_apply(v, H);
    }
  } else {
    float pc[64];
    load_row_g(QROW + lane * 64, pc);           // pc[k] = Q[lane][k]
    float u = C[d * 64 + lane];
    #pragma unroll 1
    for (int i = 0; i < NI; ++i) {
      Ud[i * 64 + lane] = u;                    // coalesced
      if (i < NI - 1) u = qapply(pc, u);        // pure VALU
    }
  }
}

// Phase 2: epilogue. One block per d: stage V_d (16KB LDS, XOR-swizzled),
// U rows from global (coalesced), K[d,i*64+j] = dot(U[i],V[j]).
__global__ __launch_bounds__(256) void hippo_epi(
    const float* __restrict__ Dv, const float* __restrict__ Vg,
    const float* __restrict__ Ug, float* __restrict__ out, int NI, int L) {
  __shared__ __align__(16) float Vl[64 * 64];   // quad-XOR swizzle
  const int d = blockIdx.x;
  const int tau = threadIdx.x;
  const int lane = tau & 63;
  const int w = tau >> 6;
  const float* Vd = Vg + (size_t)d * 4096;
  const float* Ud = Ug + (size_t)d * 2048;

  // Stage: thread t handles float4 #(t + 256p): row j = idx>>4, quad q = idx&15.
  #pragma unroll
  for (int p = 0; p < 4; ++p) {
    const int idx = tau + 256 * p;
    const int j = idx >> 4, q = idx & 15;
    float4 f = *(const float4*)(Vd + idx * 4);                 // coalesced
    *(float4*)&Vl[j * 64 + ((q ^ (j & 15)) << 2)] = f;         // swizzled
  }
  __syncthreads();

  const int j = lane;
  float ureg[8];
  #pragma unroll
  for (int k = 0; k < 8; ++k) {
    const int i = w + 4 * k;
    ureg[k] = (i < NI) ? Ud[i * 64 + lane] : 0.f;              // coalesced
  }
  float acc[8];
  #pragma unroll
  for (int k = 0; k < 8; ++k) acc[k] = 0.f;
  #pragma unroll
  for (int h = 0; h < 4; ++h) {
    float vr[16];
    #pragma unroll
    for (int q4 = 0; q4 < 4; ++q4) {
      const int q = h * 4 + q4;
      float4 f = *(const float4*)&Vl[j * 64 + ((q ^ (j & 15)) << 2)];
      vr[4*q4+0] = f.x; vr[4*q4+1] = f.y; vr[4*q4+2] = f.z; vr[4*q4+3] = f.w;
    }
    #pragma unroll
    for (int k = 0; k < 8; ++k) {
      #pragma unroll
      for (int e = 0; e < 16; ++e) {
        acc[k] = fmaf(vr[e], rl(ureg[k], 16 * h + e), acc[k]);
      }
    }
  }
  #pragma unroll
  for (int k = 0; k < 8; ++k) {
    const int i = w + 4 * k;
    if (i < NI) {
      float y = acc[k];
      if ((i | j) == 0) y += Dv[d];
      out[(size_t)d * L + i * 64 + j] = y;   // coalesced
    }
  }
}

extern "C" void kernel_launch(void* const* d_in, const int* in_sizes, int n_in,
                              void* d_out, int out_size, void* d_ws, size_t ws_size,
                              hipStream_t stream) {
  const float* B   = (const float*)d_in[0];
  const float* C   = (const float*)d_in[1];
  const float* Dv  = (const float*)d_in[2];
  const float* ldt = (const float*)d_in[3];
  const int d_model = in_sizes[2];        // 1024
  const int L = out_size / d_model;       // 2048
  const int NI = L / 64;                  // 32
  float* A32c = (float*)d_ws;                       // 16 KiB
  float* QROW = (float*)d_ws + 4096;                // 16 KiB
  float* Vg   = (float*)d_ws + 8192;                // 16 MiB (1024*64*64)
  float* Ug   = Vg + (size_t)d_model * 4096;        //  8 MiB (1024*32*64)
  hippo_pow<<<64, 64, 0, stream>>>(ldt, A32c, QROW);
  hippo_chains<<<d_model, 192, 0, stream>>>(B, C, ldt, A32c, QROW, Vg, Ug, NI);
  hippo_epi<<<d_model, 256, 0, stream>>>(Dv, Vg, Ug, (float*)d_out, NI, L);
}

// Round 7
// 39.377 us; speedup vs baseline: 1.3012x; 1.3012x over previous
//
#include <hip/hip_runtime.h>

typedef unsigned short ushort_t;
typedef unsigned int uint_t;
typedef short short8 __attribute__((ext_vector_type(8)));
typedef float f32x4 __attribute__((ext_vector_type(4)));

namespace {

template<int CTRL, int RM>
__device__ __forceinline__ float dpp_mov0(float v) {
  return __int_as_float(__builtin_amdgcn_update_dpp(
      0, __float_as_int(v), CTRL, RM, 0xF, false));
}
template<int CTRL, int RM>
__device__ __forceinline__ float dpp_mov1(float v) {
  return __int_as_float(__builtin_amdgcn_update_dpp(
      0x3f800000, __float_as_int(v), CTRL, RM, 0xF, false));
}

__device__ __forceinline__ float rl(float v, int k) {
  return __int_as_float(__builtin_amdgcn_readlane(__float_as_int(v), k));
}

// lhs = I - h*A = diag(d_n) + h r_i r_k (k<i), h=dt/2, r_n=sqrt(2n+1),
// d_n=1+h(n+1). y = A_bar x via one joint 2-var linear-recurrence DPP scan
// (HW-verified rounds 1-6, absmax 2.4e-4). Coefs hoisted (data-independent).
struct Hoist {
  float cs0, cs1, cs2, cs3, cs4, cs5;
  float gs0, gs1, gs2, gs3, gs4, gs5;
  float r, inv_d, hr, alpha, k2;
};

__device__ __forceinline__ Hoist make_hoist(float dt, int n) {
  float h = 0.5f * dt, fn = (float)n;
  float r = sqrtf(2.f * fn + 1.f);
  float d = 1.f + h * (fn + 1.f);
  float inv_d = 1.f / d;
  float g = (1.f - h * fn) * inv_d;
  float c = g - 1.f;                  // = -h r^2 / d
  Hoist H;
  H.r = r; H.inv_d = inv_d; H.hr = h * r;
  H.alpha = 1.f + h * fn;
  H.k2 = r * (2.f - d) * inv_d;
#define COEF_STEP(IDX, CTRL, RM)                                        \
  H.cs##IDX = c; H.gs##IDX = g;                                         \
  { float cP = dpp_mov0<CTRL, RM>(c);                                   \
    float gP = dpp_mov1<CTRL, RM>(g);                                   \
    c = fmaf(g, cP, c); g = g * gP; }
  COEF_STEP(0, 0x111, 0xF)   // row_shr:1
  COEF_STEP(1, 0x112, 0xF)   // row_shr:2
  COEF_STEP(2, 0x114, 0xF)   // row_shr:4
  COEF_STEP(3, 0x118, 0xF)   // row_shr:8
  COEF_STEP(4, 0x142, 0xA)   // row_bcast15 -> rows 1,3
  COEF_STEP(5, 0x143, 0xC)   // row_bcast31 -> rows 2,3
#undef COEF_STEP
  return H;
}

__device__ __forceinline__ float abar_apply(float x, const Hoist& H) {
  float w1 = H.r * x, w2 = H.k2 * x;
#define APPLY_STEP(IDX, CTRL, RM)                                       \
  { float w1P = dpp_mov0<CTRL, RM>(w1);                                 \
    float w2P = dpp_mov0<CTRL, RM>(w2);                                 \
    w2 = fmaf(H.cs##IDX, w1P, fmaf(H.gs##IDX, w2P, w2));                \
    w1 += w1P; }
  APPLY_STEP(0, 0x111, 0xF)
  APPLY_STEP(1, 0x112, 0xF)
  APPLY_STEP(2, 0x114, 0xF)
  APPLY_STEP(3, 0x118, 0xF)
  APPLY_STEP(4, 0x142, 0xA)
  APPLY_STEP(5, 0x143, 0xC)
#undef APPLY_STEP
  float tp = dpp_mov0<0x138, 0xF>(w2);           // wave_shr:1 -> T_{i-1}
  return H.inv_d * fmaf(-H.hr, w1 + tp, H.alpha * x);
}

template<int CTRL, int RM>
__device__ __forceinline__ void linrec_step(float& G, float& W) {
  float Wo = dpp_mov0<CTRL, RM>(W);
  float Go = dpp_mov1<CTRL, RM>(G);
  W = fmaf(G, Wo, W);
  G *= Go;
}
__device__ __forceinline__ float lhs_solve(float z, const Hoist& H) {
  float G = H.gs0, W = H.r * z * H.inv_d;
  linrec_step<0x111, 0xF>(G, W);
  linrec_step<0x112, 0xF>(G, W);
  linrec_step<0x114, 0xF>(G, W);
  linrec_step<0x118, 0xF>(G, W);
  linrec_step<0x142, 0xA>(G, W);
  linrec_step<0x143, 0xC>(G, W);
  float sp = dpp_mov0<0x138, 0xF>(W);
  return (z - H.hr * sp) * H.inv_d;
}

__device__ __forceinline__ float softplus_dt(float ldt) {
  return log1pf(expf(ldt)) + 1e-6f;
}

// pc[k] = M[lane][k] from global (L2-hot) into registers. VMEM only.
__device__ __forceinline__ void load_row_g(const float* __restrict__ base,
                                           float (&pc)[64]) {
  const float4* p4 = (const float4*)base;
  #pragma unroll
  for (int q = 0; q < 16; ++q) {
    float4 f = p4[q];
    pc[4*q+0] = f.x; pc[4*q+1] = f.y; pc[4*q+2] = f.z; pc[4*q+3] = f.w;
  }
}

// res[lane] = sum_k pc[k]*u[k]; u distributed, broadcast via readlane.
__device__ __forceinline__ float qapply(const float (&pc)[64], float u) {
  float a0 = 0.f, a1 = 0.f, a2 = 0.f, a3 = 0.f;
  #pragma unroll
  for (int k = 0; k < 64; k += 4) {
    a0 = fmaf(pc[k + 0], rl(u, k + 0), a0);
    a1 = fmaf(pc[k + 1], rl(u, k + 1), a1);
    a2 = fmaf(pc[k + 2], rl(u, k + 2), a2);
    a3 = fmaf(pc[k + 3], rl(u, k + 3), a3);
  }
  return (a0 + a1) + (a2 + a3);
}

// streaming matvec from global row (one float4 live at a time)
__device__ __forceinline__ float grow_matvec(const float* __restrict__ M,
                                             float u, int lane) {
  float a0 = 0.f, a1 = 0.f, a2 = 0.f, a3 = 0.f;
  const float4* m4 = (const float4*)(M + lane * 64);
  #pragma unroll
  for (int q = 0; q < 16; ++q) {
    float4 f = m4[q];
    a0 = fmaf(f.x, rl(u, 4 * q + 0), a0);
    a1 = fmaf(f.y, rl(u, 4 * q + 1), a1);
    a2 = fmaf(f.z, rl(u, 4 * q + 2), a2);
    a3 = fmaf(f.w, rl(u, 4 * q + 3), a3);
  }
  return (a0 + a1) + (a2 + a3);
}

// bf16 error-compensated split store into chunk-XOR-swizzled LDS.
// Logical chunk (n>>3) of row `row` lives at phys chunk (n>>3)^(row&7);
// 64 lanes' b16 writes span 128B -> 2 lanes/bank (free). Frag reads
// (short8, 16B) of 16 consecutive rows hit 8 distinct slots -> <=2-way.
__device__ __forceinline__ void split_store(float v, ushort_t* Hi,
                                            ushort_t* Lo, int row, int n) {
  uint_t uv = __float_as_uint(v);
  float hf = __uint_as_float(uv & 0xFFFF0000u);        // truncated hi
  uint_t lv = __float_as_uint(v - hf);                 // exact residual
  int idx = (row << 6) | (((n >> 3) ^ (row & 7)) << 3) | (n & 7);
  Hi[idx] = (ushort_t)(uv >> 16);
  Lo[idx] = (ushort_t)(lv >> 16);
}

__device__ __forceinline__ int frag_off(int row, int chunk) {
  return (row << 6) | ((chunk ^ (row & 7)) << 3);
}

} // namespace

// Prep: block m chains e_m through 128 applies.
//   s=32 : col m of A32  -> row-major A32c[n][k] (scatter)
//   s=64 : col m of A64  = Q-row m   -> QROW  (coalesced)
//   s=128: col m of A128 = Q^2-row m -> Q2ROW (coalesced)
__global__ __launch_bounds__(64) void hippo_pow(const float* __restrict__ ldt_p,
                                                float* __restrict__ A32c,
                                                float* __restrict__ QROW,
                                                float* __restrict__ Q2ROW) {
  const int lane = threadIdx.x;
  const int m = blockIdx.x;
  const float dt = softplus_dt(ldt_p[0]);
  const Hoist H = make_hoist(dt, lane);
  float x = (lane == m) ? 1.f : 0.f;
  #pragma unroll 1
  for (int s = 0; s < 32; ++s) x = abar_apply(x, H);
  A32c[lane * 64 + m] = x;
  #pragma unroll 1
  for (int s = 0; s < 32; ++s) x = abar_apply(x, H);
  QROW[m * 64 + lane] = x;
  #pragma unroll 1
  for (int s = 0; s < 64; ++s) x = abar_apply(x, H);
  Q2ROW[m * 64 + lane] = x;
}

// Main: per d. Chains write bf16 hi/lo into swizzled LDS; epilogue is
// 12 mfma_f32_16x16x32_bf16 per wave (bf16x2 split: hh + hl + lh).
//  w0: V[0..31]; w3: V[32..63] (A32 seed); w1: U even (Q^2); w2: U odd.
__global__ __launch_bounds__(256, 2) void hippo_main(
    const float* __restrict__ B, const float* __restrict__ C,
    const float* __restrict__ Dv, const float* __restrict__ ldt_p,
    const float* __restrict__ A32c, const float* __restrict__ QROW,
    const float* __restrict__ Q2ROW, float* __restrict__ out,
    int NI, int L) {
  __shared__ __align__(16) ushort_t Uh[32 * 64], Ulo[32 * 64];
  __shared__ __align__(16) ushort_t Vh[64 * 64], Vlo[64 * 64];
  const int d = blockIdx.x;
  const int tau = threadIdx.x;
  const int lane = tau & 63;
  const int w = tau >> 6;
  const float dt = softplus_dt(ldt_p[0]);

  if (w == 0) {
    const Hoist H = make_hoist(dt, lane);
    float v = lhs_solve(dt * B[d * 64 + lane], H);
    #pragma unroll 1
    for (int j = 0; j < 32; ++j) {
      split_store(v, Vh, Vlo, j, lane);
      if (j < 31) v = abar_apply(v, H);
    }
  } else if (w == 3) {
    const Hoist H = make_hoist(dt, lane);
    float bb = lhs_solve(dt * B[d * 64 + lane], H);
    float v = grow_matvec(A32c, bb, lane);      // V32 = A32 * B_bar
    #pragma unroll 1
    for (int j = 32; j < 64; ++j) {
      split_store(v, Vh, Vlo, j, lane);
      if (j < 63) v = abar_apply(v, H);
    }
  } else if (w == 1) {
    float pc[64];
    load_row_g(Q2ROW + lane * 64, pc);          // pc[k] = Q2[lane][k]
    float u = C[d * 64 + lane];
    #pragma unroll 1
    for (int a = 0; a < 16; ++a) {
      split_store(u, Uh, Ulo, 2 * a, lane);
      if (a < 15) u = qapply(pc, u);
    }
  } else {  // w == 2
    float pc[64];
    load_row_g(Q2ROW + lane * 64, pc);
    float u = grow_matvec(QROW, C[d * 64 + lane], lane);   // u1 = Q u0
    #pragma unroll 1
    for (int a = 0; a < 16; ++a) {
      split_store(u, Uh, Ulo, 2 * a + 1, lane);
      if (a < 15) u = qapply(pc, u);
    }
  }
  __syncthreads();

  // MFMA epilogue: D(32x64) = U(32x64) . V(64x64)^T, bf16x2-split.
  // Wave w -> i-tile (w&1), j-tiles {2*(w>>1), 2*(w>>1)+1}.
  const int it = w & 1;
  const int jp = w >> 1;
  const int arow = lane & 15;
  const int kg = lane >> 4;
  f32x4 acc0 = {0.f, 0.f, 0.f, 0.f};
  f32x4 acc1 = {0.f, 0.f, 0.f, 0.f};
  const int ia = (it << 4) + arow;              // U row (A-frag row)
  const int jv0 = (jp << 5) + arow;             // V row, j-tile 0
  const int jv1 = jv0 + 16;                     // V row, j-tile 1
  #pragma unroll
  for (int k0 = 0; k0 < 2; ++k0) {
    const int ci = (k0 << 2) + kg;              // logical chunk 0..7
    short8 ah = *(const short8*)&Uh[frag_off(ia, ci)];
    short8 al = *(const short8*)&Ulo[frag_off(ia, ci)];
    short8 b0h = *(const short8*)&Vh[frag_off(jv0, ci)];
    short8 b0l = *(const short8*)&Vlo[frag_off(jv0, ci)];
    short8 b1h = *(const short8*)&Vh[frag_off(jv1, ci)];
    short8 b1l = *(const short8*)&Vlo[frag_off(jv1, ci)];
    acc0 = __builtin_amdgcn_mfma_f32_16x16x32_bf16(ah, b0h, acc0, 0, 0, 0);
    acc0 = __builtin_amdgcn_mfma_f32_16x16x32_bf16(al, b0h, acc0, 0, 0, 0);
    acc0 = __builtin_amdgcn_mfma_f32_16x16x32_bf16(ah, b0l, acc0, 0, 0, 0);
    acc1 = __builtin_amdgcn_mfma_f32_16x16x32_bf16(ah, b1h, acc1, 0, 0, 0);
    acc1 = __builtin_amdgcn_mfma_f32_16x16x32_bf16(al, b1h, acc1, 0, 0, 0);
    acc1 = __builtin_amdgcn_mfma_f32_16x16x32_bf16(ah, b1l, acc1, 0, 0, 0);
  }
  // C/D layout (m89-verified): col = lane&15, row = (lane>>4)*4 + reg.
  #pragma unroll
  for (int r = 0; r < 4; ++r) {
    const int i = (it << 4) + (kg << 2) + r;
    const int j0 = (jp << 5) + arow;
    float y0 = acc0[r];
    if (i == 0 && j0 == 0) y0 += Dv[d];
    out[((size_t)d << 11) + (i << 6) + j0] = y0;
    out[((size_t)d << 11) + (i << 6) + j0 + 16] = acc1[r];
  }
}

extern "C" void kernel_launch(void* const* d_in, const int* in_sizes, int n_in,
                              void* d_out, int out_size, void* d_ws, size_t ws_size,
                              hipStream_t stream) {
  const float* B   = (const float*)d_in[0];
  const float* C   = (const float*)d_in[1];
  const float* Dv  = (const float*)d_in[2];
  const float* ldt = (const float*)d_in[3];
  const int d_model = in_sizes[2];        // 1024
  const int L = out_size / d_model;       // 2048
  const int NI = L / 64;                  // 32
  float* A32c  = (float*)d_ws;            // 16 KiB
  float* QROW  = (float*)d_ws + 4096;     // 16 KiB
  float* Q2ROW = (float*)d_ws + 8192;     // 16 KiB
  hippo_pow<<<64, 64, 0, stream>>>(ldt, A32c, QROW, Q2ROW);
  hippo_main<<<d_model, 256, 0, stream>>>(B, C, Dv, ldt, A32c, QROW, Q2ROW,
                                          (float*)d_out, NI, L);
}